// Round 11
// baseline (130.618 us; speedup 1.0000x reference)
//
#include <hip/hip_runtime.h>
#include <cmath>

#define NCLUST 64
#define TSTEPS 32
#define BATCH  64
#define DIM    4096
#define REFRAC 2
#define NTH    576               // 9 waves: 8 compute + 1 publisher/idle
#define NCOMP  512               // compute threads per block
#define NPTA   8                 // producer neurons/thread: d = tid + j*512

// Raw barrier: drain LDS ops only; global stores/loads keep floating.
#define BAR() do {                                              \
    __builtin_amdgcn_sched_barrier(0);                          \
    asm volatile("s_waitcnt lgkmcnt(0)" ::: "memory");          \
    __builtin_amdgcn_s_barrier();                               \
    __builtin_amdgcn_sched_barrier(0);                          \
} while (0)

// Shared LIF step -> bit-identical spike decisions in producer and consumer.
__device__ __forceinline__ float lif_step(float x, float casc, float th,
                                          float beta_s, float beta_m,
                                          float ombm, float vreset,
                                          float& v, float& is, int& r)
{
    float isv = fmaf(beta_s, is + casc, x);
    float vn  = fmaf(beta_m, v, ombm * isv);
    float vv  = (r > 0) ? vreset : vn;
    bool  spk = (vv >= th);
    v  = spk ? (vv - th) : vv;
    r  = spk ? REFRAC : ((r > 0) ? r - 1 : 0);
    is = isv;
    return spk ? 1.0f : 0.0f;
}

// One kernel, two roles (one-way pipeline; no same-stream serialization):
//  blocks 0..63   = PRODUCERS: r10's cascade scan (512 compute thr, cluster
//                   == lane, triple-buffered LDS counts, ONE lgkm-barrier per
//                   step, all-wave 64x64 matvec with W*gain/64 in VGPRs).
//                   Wave 8 does no x-loads/outputs; after the matvec it
//                   publishes cascade[t][b][lane] with agent-scope relaxed
//                   atomic stores, waits vmcnt(0) (only its own store in
//                   flight), then lane 0 bumps the MONOTONIC counter
//                   gCtr[b] = t+1. Single writer, write-once data, monotone
//                   flag -> race-free; gCtr memset per launch.
//  blocks 64..319 = CONSUMERS: 4 per row, 1024 neurons each (float2 I/O).
//                   Per step: compute+store with cascade(t-1) from registers;
//                   wave 0 polls gCtr[b] >= t+1, pulls the 64 cascade floats
//                   (agent-scope relaxed loads) into a double-buffered LDS
//                   slot; BAR; everyone picks up its 2 clusters' values.
//                   Consumers never write anything producers read: one-way.
// Deadlock-free: 320 blocks x 576 thr are trivially co-resident (~184k
// threads, tiny LDS, VGPR<=128).
__global__ __launch_bounds__(NTH)
void alif_fused(const float* __restrict__ x_in,      // (T,B,D)
                const float* __restrict__ threshold, // (D)
                const float* __restrict__ bm_raw,
                const float* __restrict__ bs_raw,
                const float* __restrict__ nw,        // (NC,NC)
                const float* __restrict__ gain,      // (NC)
                float* __restrict__ out_s,           // (T,B,D)
                float* __restrict__ out_v,           // (T,B,D)
                float* __restrict__ gCasc,           // (T,B,NC) ws
                unsigned int* __restrict__ gCtr)     // (B) ws, zeroed
{
    const int tid  = threadIdx.x;
    const int lane = tid & 63;
    const int wav  = tid >> 6;

    const float beta_m = 1.0f / (1.0f + expf(-bm_raw[0]));
    const float beta_s = 1.0f / (1.0f + expf(-bs_raw[0]));
    const float ombm   = 1.0f - beta_m;
    const float vreset = -0.1f;
    const size_t strideT = (size_t)BATCH * DIM;

    if (blockIdx.x < BATCH) {
        // ------------------------- PRODUCER -------------------------
        __shared__ __align__(16) float sCnt[3][NCLUST];
        const int b = blockIdx.x;

        float wReg[NCLUST];
        {
            const float g = gain[lane] * (1.0f / 64.0f);
#pragma unroll
            for (int k = 0; k < 16; k++) {
                float4 w4 = *(const float4*)(nw + lane * NCLUST + 4 * k);
                wReg[4*k+0] = g / (1.0f + expf(-w4.x));
                wReg[4*k+1] = g / (1.0f + expf(-w4.y));
                wReg[4*k+2] = g / (1.0f + expf(-w4.z));
                wReg[4*k+3] = g / (1.0f + expf(-w4.w));
            }
        }

        float v_[NPTA], is_[NPTA], th_[NPTA], xA[NPTA], xB[NPTA];
        int   r_[NPTA];
        const float* xp = x_in + (size_t)b * DIM + tid;
        if (tid < NCOMP) {
#pragma unroll
            for (int j = 0; j < NPTA; j++) {
                v_[j] = 0.f; is_[j] = 0.f; r_[j] = 0;
                th_[j] = threshold[tid + j * NCOMP];
                xA[j] = xp[j * NCOMP];
                xB[j] = xp[strideT + j * NCOMP];
            }
        }
        if (tid < 3 * NCLUST) ((float*)sCnt)[tid] = 0.f;
        __syncthreads();

        float casc = 0.f;
        int slot = 0;
        float* const gcb = gCasc + (size_t)b * NCLUST + lane;
        unsigned int* const cb = gCtr + b;

#define ASTEP(T_, XC)                                                         \
    {                                                                         \
        const int nslot = (slot == 2) ? 0 : slot + 1;                         \
        if (tid < NCOMP) {                                                    \
            float cnt = 0.f;                                                  \
            _Pragma("unroll")                                                 \
            for (int j = 0; j < NPTA; j++)                                    \
                cnt += lif_step(XC[j], casc, th_[j], beta_s, beta_m, ombm,    \
                                vreset, v_[j], is_[j], r_[j]);                \
            if (cnt != 0.f) atomicAdd(&sCnt[slot][lane], cnt);                \
            if ((T_) + 2 < TSTEPS) {                                          \
                const float* xf = xp + (size_t)((T_) + 2) * strideT;          \
                _Pragma("unroll")                                             \
                for (int j = 0; j < NPTA; j++) XC[j] = xf[j * NCOMP];         \
            }                                                                 \
        }                                                                     \
        sCnt[nslot][lane] = 0.f;   /* triple-buffer reset (r10 proof) */      \
        BAR();                                                                \
        {                                                                     \
            float a0 = 0.f, a1 = 0.f, a2 = 0.f, a3 = 0.f;                     \
            _Pragma("unroll")                                                 \
            for (int k = 0; k < 16; k++) {                                    \
                float4 c4 = *(const float4*)&sCnt[slot][4 * k];               \
                a0 = fmaf(c4.x, wReg[4*k+0], a0);                             \
                a1 = fmaf(c4.y, wReg[4*k+1], a1);                             \
                a2 = fmaf(c4.z, wReg[4*k+2], a2);                             \
                a3 = fmaf(c4.w, wReg[4*k+3], a3);                             \
            }                                                                 \
            casc = (a0 + a1) + (a2 + a3);                                     \
        }                                                                     \
        if (wav == 8) {                                                       \
            __hip_atomic_store(gcb + (size_t)(T_) * BATCH * NCLUST, casc,     \
                               __ATOMIC_RELAXED, __HIP_MEMORY_SCOPE_AGENT);   \
            __builtin_amdgcn_sched_barrier(0);                                \
            asm volatile("s_waitcnt vmcnt(0)" ::: "memory");                  \
            __builtin_amdgcn_sched_barrier(0);                                \
            if (lane == 0)                                                    \
                __hip_atomic_store(cb, (unsigned int)((T_) + 1),              \
                                   __ATOMIC_RELAXED,                          \
                                   __HIP_MEMORY_SCOPE_AGENT);                 \
        }                                                                     \
        slot = nslot;                                                         \
    }

        for (int t = 0; t < TSTEPS; t += 2) {
            ASTEP(t,     xA)
            ASTEP(t + 1, xB)
        }
#undef ASTEP
    } else {
        // ------------------------- CONSUMER -------------------------
        __shared__ __align__(16) float sC[2][NCLUST];
        const int p  = blockIdx.x - BATCH;
        const int b  = p >> 2;
        const int q  = p & 3;
        const int d0 = q * 1024 + 2 * tid;        // tid < NCOMP valid
        const int c0 = d0 & 63;                   // even

        const float* xp = x_in  + (size_t)b * DIM + d0;
        float*       sp = out_s + (size_t)b * DIM + d0;
        float*       vp = out_v + (size_t)b * DIM + d0;

        float th0 = 0.f, th1 = 0.f;
        float v0 = 0.f, is0 = 0.f, v1 = 0.f, is1 = 0.f;
        int   r0 = 0, r1 = 0;
        float2 xA = make_float2(0.f, 0.f), xB = make_float2(0.f, 0.f);
        if (tid < NCOMP) {
            th0 = threshold[d0];
            th1 = threshold[d0 + 1];
            xA = *(const float2*)xp;
            xB = *(const float2*)(xp + strideT);
        }
        __syncthreads();

        float casc0 = 0.f, casc1 = 0.f;
        const float* const gcb = gCasc + (size_t)b * NCLUST;
        unsigned int* const cb = gCtr + b;

#define BSTEP(T_, XC)                                                         \
    {                                                                         \
        if (tid < NCOMP) {                                                    \
            float s0 = lif_step(XC.x, casc0, th0, beta_s, beta_m, ombm,       \
                                vreset, v0, is0, r0);                         \
            float s1 = lif_step(XC.y, casc1, th1, beta_s, beta_m, ombm,       \
                                vreset, v1, is1, r1);                         \
            *(float2*)(sp + (size_t)(T_) * strideT) = make_float2(s0, s1);    \
            *(float2*)(vp + (size_t)(T_) * strideT) = make_float2(v0, v1);    \
            if ((T_) + 2 < TSTEPS)                                            \
                XC = *(const float2*)(xp + (size_t)((T_) + 2) * strideT);     \
        }                                                                     \
        if ((T_) + 1 < TSTEPS) {                                              \
            if (wav == 0) {                                                   \
                const unsigned int tgt = (unsigned int)((T_) + 1);            \
                while (__hip_atomic_load(cb, __ATOMIC_RELAXED,                \
                                         __HIP_MEMORY_SCOPE_AGENT) < tgt) {}  \
                sC[(T_) & 1][lane] = __hip_atomic_load(                       \
                    gcb + (size_t)(T_) * BATCH * NCLUST + lane,               \
                    __ATOMIC_RELAXED, __HIP_MEMORY_SCOPE_AGENT);              \
            }                                                                 \
            BAR();                                                            \
            casc0 = sC[(T_) & 1][c0];                                         \
            casc1 = sC[(T_) & 1][c0 + 1];                                     \
        }                                                                     \
    }

        for (int t = 0; t < TSTEPS; t += 2) {
            BSTEP(t,     xA)
            BSTEP(t + 1, xB)
        }
#undef BSTEP
    }
}

extern "C" void kernel_launch(void* const* d_in, const int* in_sizes, int n_in,
                              void* d_out, int out_size, void* d_ws, size_t ws_size,
                              hipStream_t stream) {
    const float* x  = (const float*)d_in[0];
    const float* th = (const float*)d_in[1];
    const float* bm = (const float*)d_in[2];
    const float* bs = (const float*)d_in[3];
    const float* nw = (const float*)d_in[4];
    const float* gn = (const float*)d_in[5];
    float* out_s = (float*)d_out;
    float* out_v = out_s + (size_t)TSTEPS * BATCH * DIM;

    float* gCasc = (float*)d_ws;                       // 512 KB, write-once
    unsigned int* gCtr =
        (unsigned int*)((char*)d_ws + (size_t)TSTEPS * BATCH * NCLUST * sizeof(float));

    // Zero only the monotonic counters (256 B) each launch: deterministic,
    // no cross-replay state. gCasc is flag-gated write-before-read.
    hipMemsetAsync(gCtr, 0, BATCH * sizeof(unsigned int), stream);

    hipLaunchKernelGGL(alif_fused, dim3(BATCH + BATCH * 4), dim3(NTH), 0, stream,
                       x, th, bm, bs, nw, gn, out_s, out_v, gCasc, gCtr);
}